// Round 10
// baseline (10426.071 us; speedup 1.0000x reference)
//
#include <hip/hip_runtime.h>

// Problem constants (b=8, n=1024, m=1024, d=256, RHO=1, LAMBDA=0.1, 50 iters)
// ADMM box-QP via Woodbury on A = I + 2 Vs Vs^T  (Vs = V / 1024).
//   state e (f64):  z = clip(e), s = 2z - e   (s derived from E on the fly in iterA)
//   w  = W1 @ s - Pvp            (fp32 GEMM, K=1024)   W1 = M Vs^T, Pvp = M Vs^T P
//   e' = clip(e) - P - (2/1024) * (V @ w)   (fp32 GEMM K=256 + f64 elementwise)
// R10 = R8 tiles/grids/pinning + A-operands (W1,V) read per-kk directly from
// global in k-major layout (W1T, VT) -> A-staging off the LDS pipe. Bitwise-
// identical FMA chains to R1/R8 (same values, same order).

__device__ __forceinline__ double clip01(double v) { return fmin(fmax(v, 0.0), 1.0); }

// ---------------- NT GEMM, f64 accumulate: C = (TC)(alpha * A@B^T + c0) ----------
// TRS=true stores C transposed (C_T[col][row], float4 over 4 consecutive rows).
template <typename TA, typename TC, bool TRS = false>
__global__ __launch_bounds__(256) void k_gemm_nt(
    const TA* __restrict__ Ag, const float* __restrict__ Bg, TC* __restrict__ Cg,
    int M, int N, int K, long sA, long sB, long sC, double alpha, double c0)
{
  const TA* A = Ag + (long)blockIdx.z * sA;
  const float* B = Bg + (long)blockIdx.z * sB;
  TC* C = Cg + (long)blockIdx.z * sC;
  const int m0 = blockIdx.x * 64, n0 = blockIdx.y * 64;
  const int tid = threadIdx.x;
  __shared__ double As[32][68];
  __shared__ double Bs[32][68];
  const int tx = tid & 15, ty = tid >> 4;
  const int r = tid >> 2, kq = (tid & 3) * 8;
  double acc[4][4] = {};
  for (int k0 = 0; k0 < K; k0 += 32) {
    if constexpr (sizeof(TA) == 4) {
      const float4* ap = reinterpret_cast<const float4*>(A + (size_t)(m0 + r) * K + k0 + kq);
      float4 a0 = ap[0], a1 = ap[1];
      As[kq+0][r] = a0.x; As[kq+1][r] = a0.y; As[kq+2][r] = a0.z; As[kq+3][r] = a0.w;
      As[kq+4][r] = a1.x; As[kq+5][r] = a1.y; As[kq+6][r] = a1.z; As[kq+7][r] = a1.w;
    } else {
      const double2* ap = reinterpret_cast<const double2*>(A + (size_t)(m0 + r) * K + k0 + kq);
      double2 a0 = ap[0], a1 = ap[1], a2 = ap[2], a3 = ap[3];
      As[kq+0][r] = a0.x; As[kq+1][r] = a0.y; As[kq+2][r] = a1.x; As[kq+3][r] = a1.y;
      As[kq+4][r] = a2.x; As[kq+5][r] = a2.y; As[kq+6][r] = a3.x; As[kq+7][r] = a3.y;
    }
    {
      const float4* bp = reinterpret_cast<const float4*>(B + (size_t)(n0 + r) * K + k0 + kq);
      float4 b0 = bp[0], b1 = bp[1];
      Bs[kq+0][r] = b0.x; Bs[kq+1][r] = b0.y; Bs[kq+2][r] = b0.z; Bs[kq+3][r] = b0.w;
      Bs[kq+4][r] = b1.x; Bs[kq+5][r] = b1.y; Bs[kq+6][r] = b1.z; Bs[kq+7][r] = b1.w;
    }
    __syncthreads();
#pragma unroll
    for (int kk = 0; kk < 32; ++kk) {
      double a_[4], b_[4];
#pragma unroll
      for (int i = 0; i < 4; ++i) a_[i] = As[kk][ty * 4 + i];
#pragma unroll
      for (int j = 0; j < 4; ++j) b_[j] = Bs[kk][tx * 4 + j];
#pragma unroll
      for (int i = 0; i < 4; ++i)
#pragma unroll
        for (int j = 0; j < 4; ++j) acc[i][j] = fma(a_[i], b_[j], acc[i][j]);
    }
    __syncthreads();
  }
  if constexpr (TRS) {
#pragma unroll
    for (int j = 0; j < 4; ++j) {
      int col = n0 + tx * 4 + j;
      float4 o;
      o.x = (float)(alpha * acc[0][j] + c0);
      o.y = (float)(alpha * acc[1][j] + c0);
      o.z = (float)(alpha * acc[2][j] + c0);
      o.w = (float)(alpha * acc[3][j] + c0);
      *reinterpret_cast<float4*>((float*)C + (size_t)col * M + m0 + ty * 4) = o;
    }
  } else {
#pragma unroll
    for (int i = 0; i < 4; ++i) {
      int row = m0 + ty * 4 + i;
#pragma unroll
      for (int j = 0; j < 4; ++j)
        C[(size_t)row * N + n0 + tx * 4 + j] = (TC)(alpha * acc[i][j] + c0);
    }
  }
}

// ---------------- TN GEMM, f64 accumulate: C[MxN] = scale * A^T @ B -------------
template <typename TB>
__global__ __launch_bounds__(256) void k_gemm_tn(
    const float* __restrict__ Ag, const TB* __restrict__ Bg, double* __restrict__ Cg,
    int M, int N, int K, long sA, long sB, long sC, double scale)
{
  const float* A = Ag + (long)blockIdx.z * sA;
  const TB* B = Bg + (long)blockIdx.z * sB;
  double* C = Cg + (long)blockIdx.z * sC;
  const int m0 = blockIdx.x * 64, n0 = blockIdx.y * 64;
  const int tid = threadIdx.x;
  __shared__ float As[16][68];
  __shared__ double Bs[16][68];
  const int tx = tid & 15, ty = tid >> 4;
  const int kk = tid >> 4, c4 = (tid & 15) * 4;
  double acc[4][4] = {};
  for (int k0 = 0; k0 < K; k0 += 16) {
    float4 av = *reinterpret_cast<const float4*>(A + (size_t)(k0 + kk) * M + m0 + c4);
    *reinterpret_cast<float4*>(&As[kk][c4]) = av;
    if constexpr (sizeof(TB) == 4) {
      float4 bv = *reinterpret_cast<const float4*>(B + (size_t)(k0 + kk) * N + n0 + c4);
      Bs[kk][c4 + 0] = bv.x; Bs[kk][c4 + 1] = bv.y; Bs[kk][c4 + 2] = bv.z; Bs[kk][c4 + 3] = bv.w;
    } else {
      const double2* bp = reinterpret_cast<const double2*>(B + (size_t)(k0 + kk) * N + n0 + c4);
      double2 b0 = bp[0], b1 = bp[1];
      *reinterpret_cast<double2*>(&Bs[kk][c4]) = b0;
      *reinterpret_cast<double2*>(&Bs[kk][c4 + 2]) = b1;
    }
    __syncthreads();
#pragma unroll
    for (int k = 0; k < 16; ++k) {
      double a_[4], b_[4];
#pragma unroll
      for (int i = 0; i < 4; ++i) a_[i] = (double)As[k][ty * 4 + i];
#pragma unroll
      for (int j = 0; j < 4; ++j) b_[j] = Bs[k][tx * 4 + j];
#pragma unroll
      for (int i = 0; i < 4; ++i)
#pragma unroll
        for (int j = 0; j < 4; ++j) acc[i][j] = fma(a_[i], b_[j], acc[i][j]);
    }
    __syncthreads();
  }
#pragma unroll
  for (int i = 0; i < 4; ++i) {
    int row = m0 + ty * 4 + i;
#pragma unroll
    for (int j = 0; j < 4; ++j)
      C[(size_t)row * N + n0 + tx * 4 + j] = scale * acc[i][j];
  }
}

// ---------------- Ad = I + 2G, X0 = I - 2G --------------------------------------
__global__ __launch_bounds__(256) void k_adx0(const double* __restrict__ G,
                                              double* __restrict__ Ad, double* __restrict__ X)
{
  size_t idx = (size_t)blockIdx.x * 256 + threadIdx.x;
  double g = G[idx];
  int ij = (int)(idx & 65535);
  double dg = ((ij >> 8) == (ij & 255)) ? 1.0 : 0.0;
  Ad[idx] = dg + 2.0 * g;
  X[idx] = dg - 2.0 * g;
}

// ---------------- small f64 NN GEMM: C = alpha*A@B + beta*Xin -------------------
template <bool F32OUT>
__global__ __launch_bounds__(256) void k_smallmm(
    const double* __restrict__ Ag, const double* __restrict__ Bg,
    const double* __restrict__ Xg, void* __restrict__ Cg,
    int N, long sB, long sC, double alpha, double beta)
{
  const double* A = Ag + (long)blockIdx.z * 65536;
  const double* B = Bg + (long)blockIdx.z * sB;
  const double* Xp = Xg ? (Xg + (long)blockIdx.z * sB) : (const double*)nullptr;
  const int m0 = blockIdx.x * 64, n0 = blockIdx.y * 64;
  const int tid = threadIdx.x;
  __shared__ double As[16][68];
  __shared__ double Bs[16][68];
  const int tx = tid & 15, ty = tid >> 4;
  const int ra = tid >> 2, kqa = (tid & 3) * 4;
  const int kb = tid >> 4, cb = (tid & 15) * 4;
  double acc[4][4] = {};
  for (int k0 = 0; k0 < 256; k0 += 16) {
    const double2* ap = reinterpret_cast<const double2*>(A + (size_t)(m0 + ra) * 256 + k0 + kqa);
    double2 a0 = ap[0], a1 = ap[1];
    As[kqa + 0][ra] = a0.x; As[kqa + 1][ra] = a0.y; As[kqa + 2][ra] = a1.x; As[kqa + 3][ra] = a1.y;
    const double2* bp = reinterpret_cast<const double2*>(B + (size_t)(k0 + kb) * N + n0 + cb);
    double2 b0 = bp[0], b1 = bp[1];
    *reinterpret_cast<double2*>(&Bs[kb][cb]) = b0;
    *reinterpret_cast<double2*>(&Bs[kb][cb + 2]) = b1;
    __syncthreads();
#pragma unroll
    for (int k = 0; k < 16; ++k) {
      double a_[4], b_[4];
#pragma unroll
      for (int i = 0; i < 4; ++i) a_[i] = As[k][ty * 4 + i];
#pragma unroll
      for (int j = 0; j < 4; ++j) b_[j] = Bs[k][tx * 4 + j];
#pragma unroll
      for (int i = 0; i < 4; ++i)
#pragma unroll
        for (int j = 0; j < 4; ++j) acc[i][j] = fma(a_[i], b_[j], acc[i][j]);
    }
    __syncthreads();
  }
#pragma unroll
  for (int i = 0; i < 4; ++i) {
    int row = m0 + ty * 4 + i;
#pragma unroll
    for (int j = 0; j < 4; ++j) {
      int col = n0 + tx * 4 + j;
      double v = alpha * acc[i][j];
      if (beta != 0.0) v = fma(beta, Xp[(size_t)row * N + col], v);
      if constexpr (F32OUT)
        ((float*)Cg)[(long)blockIdx.z * sC + (size_t)row * N + col] = (float)v;
      else
        ((double*)Cg)[(long)blockIdx.z * sC + (size_t)row * N + col] = v;
    }
  }
}

// ---------------- plain transpose: out[c][r] = in[r][c] -------------------------
__global__ __launch_bounds__(256) void k_transpose(
    const float* __restrict__ in, float* __restrict__ out, int R, int C)
{
  __shared__ float t[32][33];
  const float* ip = in + (size_t)blockIdx.z * R * C;
  float* op = out + (size_t)blockIdx.z * R * C;
  const int r0 = blockIdx.x * 32, c0 = blockIdx.y * 32;
  const int tx = threadIdx.x & 31, ty = threadIdx.x >> 5;
#pragma unroll
  for (int i = 0; i < 4; ++i)
    t[ty + i * 8][tx] = ip[(size_t)(r0 + ty + i * 8) * C + c0 + tx];
  __syncthreads();
#pragma unroll
  for (int i = 0; i < 4; ++i)
    op[(size_t)(c0 + ty + i * 8) * R + r0 + tx] = t[tx][ty + i * 8];
}

// ---------------- per-iter GEMM A (fp32): w = W1 @ s - Pvp ----------------------
// A-frags read per-kk from W1T (k-major, [1024][256]); B = s derived on the fly
// from E (f64). BM=64,BN=128,BK=32, micro 4x8. grid (32,8): x = mt*8 + b.
__global__ __launch_bounds__(256) void k_iterA6(
    const float* __restrict__ W1Tg, const double* __restrict__ Eg,
    const float* __restrict__ Pvg, float* __restrict__ Wg)
{
  const int b = blockIdx.x & 7, mt = blockIdx.x >> 3;
  const float* AT = W1Tg + (size_t)b * 262144;    // [1024][256]
  const double* Ee = Eg + (size_t)b * 1048576;    // [1024][1024]
  const float* Pv = Pvg + (size_t)b * 262144;
  float* C = Wg + (size_t)b * 262144;
  const int m0 = mt * 64, n0 = blockIdx.y * 128;
  const int tid = threadIdx.x;
  __shared__ float Bs[32][132];
  const int tx = tid & 15, ty = tid >> 4;
  const int rb = tid >> 5, cb = (tid & 31) * 4;
  float acc[4][8] = {};
  for (int k0 = 0; k0 < 1024; k0 += 32) {
#pragma unroll
    for (int p = 0; p < 4; ++p) {
      int krow = rb + p * 8;
      const double* erow = Ee + (size_t)(k0 + krow) * 1024 + n0 + cb;
      double2 e0 = *reinterpret_cast<const double2*>(erow);
      double2 e1 = *reinterpret_cast<const double2*>(erow + 2);
      float4 v;
      v.x = (float)(2.0 * clip01(e0.x) - e0.x);
      v.y = (float)(2.0 * clip01(e0.y) - e0.y);
      v.z = (float)(2.0 * clip01(e1.x) - e1.x);
      v.w = (float)(2.0 * clip01(e1.y) - e1.y);
      *reinterpret_cast<float4*>(&Bs[krow][cb]) = v;
    }
    __syncthreads();
#pragma unroll
    for (int kk = 0; kk < 32; ++kk) {
      float4 av = *reinterpret_cast<const float4*>(AT + (size_t)(k0 + kk) * 256 + m0 + ty * 4);
      float4 b0 = *reinterpret_cast<const float4*>(&Bs[kk][tx * 8]);
      float4 b1 = *reinterpret_cast<const float4*>(&Bs[kk][tx * 8 + 4]);
      float a_[4] = {av.x, av.y, av.z, av.w};
      float b_[8] = {b0.x, b0.y, b0.z, b0.w, b1.x, b1.y, b1.z, b1.w};
#pragma unroll
      for (int i = 0; i < 4; ++i)
#pragma unroll
        for (int j = 0; j < 8; ++j) acc[i][j] = fmaf(a_[i], b_[j], acc[i][j]);
    }
    __syncthreads();
  }
#pragma unroll
  for (int i = 0; i < 4; ++i) {
    size_t base = (size_t)(m0 + ty * 4 + i) * 1024 + n0 + tx * 8;
    float4 p0 = *reinterpret_cast<const float4*>(Pv + base);
    float4 p1 = *reinterpret_cast<const float4*>(Pv + base + 4);
    float4 o0, o1;
    o0.x = acc[i][0] - p0.x; o0.y = acc[i][1] - p0.y; o0.z = acc[i][2] - p0.z; o0.w = acc[i][3] - p0.w;
    o1.x = acc[i][4] - p1.x; o1.y = acc[i][5] - p1.y; o1.z = acc[i][6] - p1.z; o1.w = acc[i][7] - p1.w;
    *reinterpret_cast<float4*>(C + base) = o0;
    *reinterpret_cast<float4*>(C + base + 4) = o1;
  }
}

// ---------------- per-iter fused GEMM C + elementwise ---------------------------
// g = V @ w ; e' = clip(e) - P - (2/1024)*g  (f64, no s store).
// A-frags read per-kk from VT (k-major, [256][1024]). BM=BN=128, BK=16, micro 8x8.
// grid (64, 8): x = mt*8 + b.
__global__ __launch_bounds__(256) void k_iterC6(
    const float* __restrict__ VTg, const float* __restrict__ Wg,
    const double* __restrict__ Pg, double* __restrict__ Eg)
{
  const int b = blockIdx.x & 7, mt = blockIdx.x >> 3;
  const float* AT = VTg + (size_t)b * 262144;     // [256][1024]
  const float* B = Wg + (size_t)b * 262144;
  const double* P = Pg + (size_t)b * 1048576;
  double* E = Eg + (size_t)b * 1048576;
  const int m0 = mt * 128, n0 = blockIdx.y * 128;
  const int tid = threadIdx.x;
  __shared__ float Bs[16][132];
  const int tx = tid & 15, ty = tid >> 4;
  const int rb = tid >> 5, cb = (tid & 31) * 4;
  float acc[8][8] = {};
  for (int k0 = 0; k0 < 256; k0 += 16) {
#pragma unroll
    for (int p = 0; p < 2; ++p) {
      int krow = rb + p * 8;
      float4 bv = *reinterpret_cast<const float4*>(B + (size_t)(k0 + krow) * 1024 + n0 + cb);
      *reinterpret_cast<float4*>(&Bs[krow][cb]) = bv;
    }
    __syncthreads();
#pragma unroll
    for (int kk = 0; kk < 16; ++kk) {
      float4 a0 = *reinterpret_cast<const float4*>(AT + (size_t)(k0 + kk) * 1024 + m0 + ty * 8);
      float4 a1 = *reinterpret_cast<const float4*>(AT + (size_t)(k0 + kk) * 1024 + m0 + ty * 8 + 4);
      float4 b0 = *reinterpret_cast<const float4*>(&Bs[kk][tx * 8]);
      float4 b1 = *reinterpret_cast<const float4*>(&Bs[kk][tx * 8 + 4]);
      float a_[8] = {a0.x, a0.y, a0.z, a0.w, a1.x, a1.y, a1.z, a1.w};
      float b_[8] = {b0.x, b0.y, b0.z, b0.w, b1.x, b1.y, b1.z, b1.w};
#pragma unroll
      for (int i = 0; i < 8; ++i)
#pragma unroll
        for (int j = 0; j < 8; ++j) acc[i][j] = fmaf(a_[i], b_[j], acc[i][j]);
    }
    __syncthreads();
  }
  const double cg = 2.0 / 1024.0;
#pragma unroll
  for (int ii = 0; ii < 8; ++ii) {
    size_t base = (size_t)(m0 + ty * 8 + ii) * 1024 + n0 + tx * 8;
    double e_[8], p_[8];
#pragma unroll
    for (int q = 0; q < 4; ++q) {
      double2 ev = *reinterpret_cast<const double2*>(E + base + 2 * q);
      double2 pv = *reinterpret_cast<const double2*>(P + base + 2 * q);
      e_[2 * q] = ev.x; e_[2 * q + 1] = ev.y;
      p_[2 * q] = pv.x; p_[2 * q + 1] = pv.y;
    }
#pragma unroll
    for (int j = 0; j < 8; ++j) {
      double z = clip01(e_[j]);
      e_[j] = z - p_[j] - cg * (double)acc[ii][j];
    }
#pragma unroll
    for (int q = 0; q < 4; ++q) {
      double2 ev; ev.x = e_[2 * q]; ev.y = e_[2 * q + 1];
      *reinterpret_cast<double2*>(E + base + 2 * q) = ev;
    }
  }
}

// ---------------- per-(b,n) count -> inverse scale ------------------------------
__global__ __launch_bounds__(256) void k_count(const double* __restrict__ Eg, float* __restrict__ inv)
{
  const int bz = blockIdx.y;
  const int j = blockIdx.x * 256 + threadIdx.x;
  const double* E = Eg + (size_t)bz * 1048576;
  int c = 0;
  for (int i = 0; i < 1024; ++i) c += (E[(size_t)i * 1024 + j] > 0.5) ? 1 : 0;
  inv[bz * 1024 + j] = (float)(1.0 / (((double)c) + 1e-10) / 1024.0);
}

// ---------------- output masked GEMM: out[j,dd] = inv[j] * sum_i mask(e) V[i,dd] --
__global__ __launch_bounds__(256) void k_out(
    const double* __restrict__ Eg, const float* __restrict__ Vg,
    const float* __restrict__ invg, float* __restrict__ Og)
{
  const double* E = Eg + (size_t)blockIdx.z * 1048576;
  const float* Vv = Vg + (size_t)blockIdx.z * 262144;
  const float* inv = invg + blockIdx.z * 1024;
  float* O = Og + (size_t)blockIdx.z * 262144;
  const int j0 = blockIdx.x * 64, d0 = blockIdx.y * 128;
  const int tid = threadIdx.x;
  __shared__ float As[32][68];
  __shared__ float Bs[32][132];
  const int tx = tid & 15, ty = tid >> 4;
  const int ka = tid >> 3, ja = (tid & 7) * 8;
  const int rb = tid >> 5, cbo = (tid & 31) * 4;
  float acc[4][8] = {};
  for (int k0 = 0; k0 < 1024; k0 += 32) {
    {
      const double2* ep = reinterpret_cast<const double2*>(E + (size_t)(k0 + ka) * 1024 + j0 + ja);
      double2 e0 = ep[0], e1 = ep[1], e2 = ep[2], e3 = ep[3];
      As[ka][ja + 0] = (e0.x > 0.5) ? 1.0f : 0.0f;
      As[ka][ja + 1] = (e0.y > 0.5) ? 1.0f : 0.0f;
      As[ka][ja + 2] = (e1.x > 0.5) ? 1.0f : 0.0f;
      As[ka][ja + 3] = (e1.y > 0.5) ? 1.0f : 0.0f;
      As[ka][ja + 4] = (e2.x > 0.5) ? 1.0f : 0.0f;
      As[ka][ja + 5] = (e2.y > 0.5) ? 1.0f : 0.0f;
      As[ka][ja + 6] = (e3.x > 0.5) ? 1.0f : 0.0f;
      As[ka][ja + 7] = (e3.y > 0.5) ? 1.0f : 0.0f;
    }
#pragma unroll
    for (int p = 0; p < 4; ++p) {
      int krow = rb + p * 8;
      float4 bv = *reinterpret_cast<const float4*>(Vv + (size_t)(k0 + krow) * 256 + d0 + cbo);
      *reinterpret_cast<float4*>(&Bs[krow][cbo]) = bv;
    }
    __syncthreads();
#pragma unroll
    for (int kk = 0; kk < 32; ++kk) {
      float4 av = *reinterpret_cast<const float4*>(&As[kk][ty * 4]);
      float4 b0 = *reinterpret_cast<const float4*>(&Bs[kk][tx * 8]);
      float4 b1 = *reinterpret_cast<const float4*>(&Bs[kk][tx * 8 + 4]);
      float a_[4] = {av.x, av.y, av.z, av.w};
      float b_[8] = {b0.x, b0.y, b0.z, b0.w, b1.x, b1.y, b1.z, b1.w};
#pragma unroll
      for (int i = 0; i < 4; ++i)
#pragma unroll
        for (int j = 0; j < 8; ++j) acc[i][j] = fmaf(a_[i], b_[j], acc[i][j]);
    }
    __syncthreads();
  }
#pragma unroll
  for (int i = 0; i < 4; ++i) {
    int row = j0 + ty * 4 + i;
    float sc = inv[row];
    size_t base = (size_t)row * 256 + d0 + tx * 8;
    float4 o0 = {acc[i][0] * sc, acc[i][1] * sc, acc[i][2] * sc, acc[i][3] * sc};
    float4 o1 = {acc[i][4] * sc, acc[i][5] * sc, acc[i][6] * sc, acc[i][7] * sc};
    *reinterpret_cast<float4*>(O + base) = o0;
    *reinterpret_cast<float4*>(O + base + 4) = o1;
  }
}

extern "C" void kernel_launch(void* const* d_in, const int* in_sizes, int n_in,
                              void* d_out, int out_size, void* d_ws, size_t ws_size,
                              hipStream_t stream)
{
  const float* Q = (const float*)d_in[0];   // (8,1024,256)
  const float* V = (const float*)d_in[1];   // (8,1024,256)
  float* out = (float*)d_out;               // (8,1024,256)
  char* ws = (char*)d_ws;

  // workspace layout (bytes) — total ~193 MB (same extent as rounds 1/8)
  const size_t OFF_E   = 0;                  // e state, f64 (8,1024,1024)   67MB
  const size_t OFF_P   = 67108864;           // P, f64 (8,1024,1024)         67MB
  const size_t SCR     = 134217728;          // scratch region (33.5 MB)
  const size_t OFF_G   = SCR;
  const size_t OFF_AD  = SCR + 4194304;
  const size_t OFF_X   = SCR + 8388608;
  const size_t OFF_Y   = SCR + 12582912;
  const size_t OFF_X2  = SCR + 16777216;     // final M (20.9MB mark)
  const size_t OFF_PV64= SCR;                // f64 (8,256,1024) overlays G..Y
  const size_t OFF_VT  = SCR;                // fp32 VT (8,256,1024) 8MB — after PV64 dead
  const size_t OFF_W   = 167772160;          // fp32 w (8,256,1024)
  const size_t OFF_W1T = 176160768;          // fp32 W1T (8,1024,256) — transposed-store GEMM
  const size_t OFF_PVP = 184549376;          // fp32 Pvp (8,256,1024)
  const size_t OFF_INV = 192937984;          // fp32 (8,1024)

  double* E    = (double*)(ws + OFF_E);
  double* P    = (double*)(ws + OFF_P);
  double* G    = (double*)(ws + OFF_G);
  double* Ad   = (double*)(ws + OFF_AD);
  double* X    = (double*)(ws + OFF_X);
  double* Y    = (double*)(ws + OFF_Y);
  double* X2   = (double*)(ws + OFF_X2);
  double* PV64 = (double*)(ws + OFF_PV64);
  float*  VT   = (float*)(ws + OFF_VT);
  float*  W    = (float*)(ws + OFF_W);
  float*  W1T  = (float*)(ws + OFF_W1T);
  float*  PVP  = (float*)(ws + OFF_PVP);
  float*  INV  = (float*)(ws + OFF_INV);

  (void)in_sizes; (void)n_in; (void)out_size; (void)ws_size;

  // e = 0
  hipMemsetAsync(ws + OFF_E, 0, 67108864, stream);

  // P = (-2/1024) * V @ Q^T + 0.1/1024     (f64, K=256)
  k_gemm_nt<float, double><<<dim3(16, 16, 8), 256, 0, stream>>>(
      V, Q, P, 1024, 1024, 256, 262144, 262144, 1048576, -2.0 / 1024.0, 0.1 / 1024.0);

  // G = (1/1024^2) V^T @ V   (f64, 256x256)
  k_gemm_tn<float><<<dim3(4, 4, 8), 256, 0, stream>>>(
      V, V, G, 256, 256, 1024, 262144, 262144, 65536, 1.0 / 1048576.0);

  // Ad = I + 2G, X0 = I - 2G
  k_adx0<<<dim3(2048), 256, 0, stream>>>(G, Ad, X);

  // Newton-Schulz x3: X <- X(2I - Ad X); final M in X2
  for (int it = 0; it < 3; ++it) {
    const double* Xc = (it % 2 == 0) ? X : X2;
    double* Xn = (it % 2 == 0) ? X2 : X;
    k_smallmm<false><<<dim3(4, 4, 8), 256, 0, stream>>>(
        Ad, Xc, (const double*)nullptr, (void*)Y, 256, 65536, 65536, 1.0, 0.0);
    k_smallmm<false><<<dim3(4, 4, 8), 256, 0, stream>>>(
        Xc, Y, Xc, (void*)Xn, 256, 65536, 65536, -1.0, 2.0);
  }

  // PV64 = (1/1024) V^T @ P   (f64, 256x1024)
  k_gemm_tn<double><<<dim3(4, 16, 8), 256, 0, stream>>>(
      V, P, PV64, 256, 1024, 1024, 262144, 1048576, 262144, 1.0 / 1024.0);

  // PVP = M @ PV64  (fp32 out)
  k_smallmm<true><<<dim3(4, 16, 8), 256, 0, stream>>>(
      X2, PV64, (const double*)nullptr, (void*)PVP, 1024, 262144, 262144, 1.0, 0.0);

  // W1T = transpose of (1/1024) M @ V^T  (fp32, stored k-major [1024][256])
  k_gemm_nt<double, float, true><<<dim3(4, 16, 8), 256, 0, stream>>>(
      X2, V, W1T, 256, 1024, 256, 65536, 262144, 262144, 1.0 / 1024.0, 0.0);

  // VT = V^T  (fp32 [256][1024]) — PV64 dead now, overlays its region
  k_transpose<<<dim3(32, 8, 8), 256, 0, stream>>>(V, VT, 1024, 256);

  // 50 ADMM iterations (XCD-pinned grids: bid%8 == batch)
  for (int t = 0; t < 50; ++t) {
    k_iterA6<<<dim3(32, 8), 256, 0, stream>>>(W1T, E, PVP, W);
    k_iterC6<<<dim3(64, 8), 256, 0, stream>>>(VT, W, P, E);
  }

  // epilogue
  k_count<<<dim3(4, 8), 256, 0, stream>>>(E, INV);
  k_out<<<dim3(16, 2, 8), 256, 0, stream>>>(E, V, INV, out);
}

// Round 11
// 8044.790 us; speedup vs baseline: 1.2960x; 1.2960x over previous
//
#include <hip/hip_runtime.h>

// Problem constants (b=8, n=1024, m=1024, d=256, RHO=1, LAMBDA=0.1, 50 iters)
// ADMM box-QP via Woodbury on A = I + 2 Vs Vs^T  (Vs = V / 1024).
//   state e (f64):  z = clip(e), s = 2z - e   (s derived from E in iterA B-stage)
//   w  = W1 @ s - Pvp   (fp32, K=1024, K-split-2 partials; -Pvp folded into iterC)
//   e' = clip(e) - P - (2/1024) * (V @ w)   (fp32 GEMM K=256 + f64 elementwise)
// R11 = R8 + iterA micro 8x8 (LDS reads/FMA halved) + bank-conflict-free
// B-read columns (tx*4 / tx*4+64) in both iter kernels. No inner-loop VMEM added.

__device__ __forceinline__ double clip01(double v) { return fmin(fmax(v, 0.0), 1.0); }

// ---------------- NT GEMM, f64 accumulate: C = (TC)(alpha * A@B^T + c0) ----------
template <typename TA, typename TC>
__global__ __launch_bounds__(256) void k_gemm_nt(
    const TA* __restrict__ Ag, const float* __restrict__ Bg, TC* __restrict__ Cg,
    int M, int N, int K, long sA, long sB, long sC, double alpha, double c0)
{
  const TA* A = Ag + (long)blockIdx.z * sA;
  const float* B = Bg + (long)blockIdx.z * sB;
  TC* C = Cg + (long)blockIdx.z * sC;
  const int m0 = blockIdx.x * 64, n0 = blockIdx.y * 64;
  const int tid = threadIdx.x;
  __shared__ double As[32][68];
  __shared__ double Bs[32][68];
  const int tx = tid & 15, ty = tid >> 4;
  const int r = tid >> 2, kq = (tid & 3) * 8;
  double acc[4][4] = {};
  for (int k0 = 0; k0 < K; k0 += 32) {
    if constexpr (sizeof(TA) == 4) {
      const float4* ap = reinterpret_cast<const float4*>(A + (size_t)(m0 + r) * K + k0 + kq);
      float4 a0 = ap[0], a1 = ap[1];
      As[kq+0][r] = a0.x; As[kq+1][r] = a0.y; As[kq+2][r] = a0.z; As[kq+3][r] = a0.w;
      As[kq+4][r] = a1.x; As[kq+5][r] = a1.y; As[kq+6][r] = a1.z; As[kq+7][r] = a1.w;
    } else {
      const double2* ap = reinterpret_cast<const double2*>(A + (size_t)(m0 + r) * K + k0 + kq);
      double2 a0 = ap[0], a1 = ap[1], a2 = ap[2], a3 = ap[3];
      As[kq+0][r] = a0.x; As[kq+1][r] = a0.y; As[kq+2][r] = a1.x; As[kq+3][r] = a1.y;
      As[kq+4][r] = a2.x; As[kq+5][r] = a2.y; As[kq+6][r] = a3.x; As[kq+7][r] = a3.y;
    }
    {
      const float4* bp = reinterpret_cast<const float4*>(B + (size_t)(n0 + r) * K + k0 + kq);
      float4 b0 = bp[0], b1 = bp[1];
      Bs[kq+0][r] = b0.x; Bs[kq+1][r] = b0.y; Bs[kq+2][r] = b0.z; Bs[kq+3][r] = b0.w;
      Bs[kq+4][r] = b1.x; Bs[kq+5][r] = b1.y; Bs[kq+6][r] = b1.z; Bs[kq+7][r] = b1.w;
    }
    __syncthreads();
#pragma unroll
    for (int kk = 0; kk < 32; ++kk) {
      double a_[4], b_[4];
#pragma unroll
      for (int i = 0; i < 4; ++i) a_[i] = As[kk][ty * 4 + i];
#pragma unroll
      for (int j = 0; j < 4; ++j) b_[j] = Bs[kk][tx * 4 + j];
#pragma unroll
      for (int i = 0; i < 4; ++i)
#pragma unroll
        for (int j = 0; j < 4; ++j) acc[i][j] = fma(a_[i], b_[j], acc[i][j]);
    }
    __syncthreads();
  }
#pragma unroll
  for (int i = 0; i < 4; ++i) {
    int row = m0 + ty * 4 + i;
#pragma unroll
    for (int j = 0; j < 4; ++j)
      C[(size_t)row * N + n0 + tx * 4 + j] = (TC)(alpha * acc[i][j] + c0);
  }
}

// ---------------- TN GEMM, f64 accumulate: C[MxN] = scale * A^T @ B -------------
template <typename TB>
__global__ __launch_bounds__(256) void k_gemm_tn(
    const float* __restrict__ Ag, const TB* __restrict__ Bg, double* __restrict__ Cg,
    int M, int N, int K, long sA, long sB, long sC, double scale)
{
  const float* A = Ag + (long)blockIdx.z * sA;
  const TB* B = Bg + (long)blockIdx.z * sB;
  double* C = Cg + (long)blockIdx.z * sC;
  const int m0 = blockIdx.x * 64, n0 = blockIdx.y * 64;
  const int tid = threadIdx.x;
  __shared__ float As[16][68];
  __shared__ double Bs[16][68];
  const int tx = tid & 15, ty = tid >> 4;
  const int kk = tid >> 4, c4 = (tid & 15) * 4;
  double acc[4][4] = {};
  for (int k0 = 0; k0 < K; k0 += 16) {
    float4 av = *reinterpret_cast<const float4*>(A + (size_t)(k0 + kk) * M + m0 + c4);
    *reinterpret_cast<float4*>(&As[kk][c4]) = av;
    if constexpr (sizeof(TB) == 4) {
      float4 bv = *reinterpret_cast<const float4*>(B + (size_t)(k0 + kk) * N + n0 + c4);
      Bs[kk][c4 + 0] = bv.x; Bs[kk][c4 + 1] = bv.y; Bs[kk][c4 + 2] = bv.z; Bs[kk][c4 + 3] = bv.w;
    } else {
      const double2* bp = reinterpret_cast<const double2*>(B + (size_t)(k0 + kk) * N + n0 + c4);
      double2 b0 = bp[0], b1 = bp[1];
      *reinterpret_cast<double2*>(&Bs[kk][c4]) = b0;
      *reinterpret_cast<double2*>(&Bs[kk][c4 + 2]) = b1;
    }
    __syncthreads();
#pragma unroll
    for (int k = 0; k < 16; ++k) {
      double a_[4], b_[4];
#pragma unroll
      for (int i = 0; i < 4; ++i) a_[i] = (double)As[k][ty * 4 + i];
#pragma unroll
      for (int j = 0; j < 4; ++j) b_[j] = Bs[k][tx * 4 + j];
#pragma unroll
      for (int i = 0; i < 4; ++i)
#pragma unroll
        for (int j = 0; j < 4; ++j) acc[i][j] = fma(a_[i], b_[j], acc[i][j]);
    }
    __syncthreads();
  }
#pragma unroll
  for (int i = 0; i < 4; ++i) {
    int row = m0 + ty * 4 + i;
#pragma unroll
    for (int j = 0; j < 4; ++j)
      C[(size_t)row * N + n0 + tx * 4 + j] = scale * acc[i][j];
  }
}

// ---------------- Ad = I + 2G, X0 = I - 2G --------------------------------------
__global__ __launch_bounds__(256) void k_adx0(const double* __restrict__ G,
                                              double* __restrict__ Ad, double* __restrict__ X)
{
  size_t idx = (size_t)blockIdx.x * 256 + threadIdx.x;
  double g = G[idx];
  int ij = (int)(idx & 65535);
  double dg = ((ij >> 8) == (ij & 255)) ? 1.0 : 0.0;
  Ad[idx] = dg + 2.0 * g;
  X[idx] = dg - 2.0 * g;
}

// ---------------- small f64 NN GEMM: C = alpha*A@B + beta*Xin -------------------
template <bool F32OUT>
__global__ __launch_bounds__(256) void k_smallmm(
    const double* __restrict__ Ag, const double* __restrict__ Bg,
    const double* __restrict__ Xg, void* __restrict__ Cg,
    int N, long sB, long sC, double alpha, double beta)
{
  const double* A = Ag + (long)blockIdx.z * 65536;
  const double* B = Bg + (long)blockIdx.z * sB;
  const double* Xp = Xg ? (Xg + (long)blockIdx.z * sB) : (const double*)nullptr;
  const int m0 = blockIdx.x * 64, n0 = blockIdx.y * 64;
  const int tid = threadIdx.x;
  __shared__ double As[16][68];
  __shared__ double Bs[16][68];
  const int tx = tid & 15, ty = tid >> 4;
  const int ra = tid >> 2, kqa = (tid & 3) * 4;
  const int kb = tid >> 4, cb = (tid & 15) * 4;
  double acc[4][4] = {};
  for (int k0 = 0; k0 < 256; k0 += 16) {
    const double2* ap = reinterpret_cast<const double2*>(A + (size_t)(m0 + ra) * 256 + k0 + kqa);
    double2 a0 = ap[0], a1 = ap[1];
    As[kqa + 0][ra] = a0.x; As[kqa + 1][ra] = a0.y; As[kqa + 2][ra] = a1.x; As[kqa + 3][ra] = a1.y;
    const double2* bp = reinterpret_cast<const double2*>(B + (size_t)(k0 + kb) * N + n0 + cb);
    double2 b0 = bp[0], b1 = bp[1];
    *reinterpret_cast<double2*>(&Bs[kb][cb]) = b0;
    *reinterpret_cast<double2*>(&Bs[kb][cb + 2]) = b1;
    __syncthreads();
#pragma unroll
    for (int k = 0; k < 16; ++k) {
      double a_[4], b_[4];
#pragma unroll
      for (int i = 0; i < 4; ++i) a_[i] = As[k][ty * 4 + i];
#pragma unroll
      for (int j = 0; j < 4; ++j) b_[j] = Bs[k][tx * 4 + j];
#pragma unroll
      for (int i = 0; i < 4; ++i)
#pragma unroll
        for (int j = 0; j < 4; ++j) acc[i][j] = fma(a_[i], b_[j], acc[i][j]);
    }
    __syncthreads();
  }
#pragma unroll
  for (int i = 0; i < 4; ++i) {
    int row = m0 + ty * 4 + i;
#pragma unroll
    for (int j = 0; j < 4; ++j) {
      int col = n0 + tx * 4 + j;
      double v = alpha * acc[i][j];
      if (beta != 0.0) v = fma(beta, Xp[(size_t)row * N + col], v);
      if constexpr (F32OUT)
        ((float*)Cg)[(long)blockIdx.z * sC + (size_t)row * N + col] = (float)v;
      else
        ((double*)Cg)[(long)blockIdx.z * sC + (size_t)row * N + col] = v;
    }
  }
}

// ---------------- iter GEMM A: wP[kc] = W1[:, kc-half] @ s[kc-half, :] ----------
// s derived from E on the fly: s = (float)(2*clip(e) - e). No Pvp here.
// BM=128, BN=128, BK=16, micro 8x8. grid (32,8): x = ((mt*2+kc)<<3)|b, y = nt.
__global__ __launch_bounds__(256) void k_iterA8(
    const float* __restrict__ W1g, const double* __restrict__ Eg,
    float* __restrict__ WPg)
{
  const int b = blockIdx.x & 7, kc = (blockIdx.x >> 3) & 1, mt = blockIdx.x >> 4;
  const float* A = W1g + (size_t)b * 262144;      // [256][1024]
  const double* Ee = Eg + (size_t)b * 1048576;    // [1024][1024]
  float* C = WPg + ((size_t)kc * 8 + b) * 262144; // [2][8][256][1024]
  const int m0 = mt * 128, n0 = blockIdx.y * 128;
  const int kbase = kc * 512;
  const int tid = threadIdx.x;
  __shared__ float As[16][132];
  __shared__ float Bs[16][132];
  const int tx = tid & 15, ty = tid >> 4;
  const int ra = tid >> 1, qa = (tid & 1) * 8;    // A stage: row, k-half
  const int kb = tid >> 4, c8 = (tid & 15) * 8;   // B stage
  float acc[8][8] = {};
  for (int k0 = 0; k0 < 512; k0 += 16) {
    // stage A: W1 tile -> As[k][m]
    {
      const float4* ap = reinterpret_cast<const float4*>(A + (size_t)(m0 + ra) * 1024 + kbase + k0 + qa);
      float4 a0 = ap[0], a1 = ap[1];
      As[qa + 0][ra] = a0.x; As[qa + 1][ra] = a0.y; As[qa + 2][ra] = a0.z; As[qa + 3][ra] = a0.w;
      As[qa + 4][ra] = a1.x; As[qa + 5][ra] = a1.y; As[qa + 6][ra] = a1.z; As[qa + 7][ra] = a1.w;
    }
    // stage B: read E rows, convert to s
    {
      const double* erow = Ee + (size_t)(kbase + k0 + kb) * 1024 + n0 + c8;
      double2 e0 = *reinterpret_cast<const double2*>(erow);
      double2 e1 = *reinterpret_cast<const double2*>(erow + 2);
      double2 e2 = *reinterpret_cast<const double2*>(erow + 4);
      double2 e3 = *reinterpret_cast<const double2*>(erow + 6);
      float4 v0, v1;
      v0.x = (float)(2.0 * clip01(e0.x) - e0.x);
      v0.y = (float)(2.0 * clip01(e0.y) - e0.y);
      v0.z = (float)(2.0 * clip01(e1.x) - e1.x);
      v0.w = (float)(2.0 * clip01(e1.y) - e1.y);
      v1.x = (float)(2.0 * clip01(e2.x) - e2.x);
      v1.y = (float)(2.0 * clip01(e2.y) - e2.y);
      v1.z = (float)(2.0 * clip01(e3.x) - e3.x);
      v1.w = (float)(2.0 * clip01(e3.y) - e3.y);
      *reinterpret_cast<float4*>(&Bs[kb][c8]) = v0;
      *reinterpret_cast<float4*>(&Bs[kb][c8 + 4]) = v1;
    }
    __syncthreads();
#pragma unroll
    for (int kk = 0; kk < 16; ++kk) {
      float4 a0 = *reinterpret_cast<const float4*>(&As[kk][ty * 8]);
      float4 a1 = *reinterpret_cast<const float4*>(&As[kk][ty * 8 + 4]);
      float4 b0 = *reinterpret_cast<const float4*>(&Bs[kk][tx * 4]);        // cols tx*4..+3
      float4 b1 = *reinterpret_cast<const float4*>(&Bs[kk][tx * 4 + 64]);   // cols 64+tx*4..+3
      float a_[8] = {a0.x, a0.y, a0.z, a0.w, a1.x, a1.y, a1.z, a1.w};
      float b_[8] = {b0.x, b0.y, b0.z, b0.w, b1.x, b1.y, b1.z, b1.w};
#pragma unroll
      for (int i = 0; i < 8; ++i)
#pragma unroll
        for (int j = 0; j < 8; ++j) acc[i][j] = fmaf(a_[i], b_[j], acc[i][j]);
    }
    __syncthreads();
  }
#pragma unroll
  for (int i = 0; i < 8; ++i) {
    size_t base = (size_t)(m0 + ty * 8 + i) * 1024 + n0 + tx * 4;
    float4 o0; o0.x = acc[i][0]; o0.y = acc[i][1]; o0.z = acc[i][2]; o0.w = acc[i][3];
    float4 o1; o1.x = acc[i][4]; o1.y = acc[i][5]; o1.z = acc[i][6]; o1.w = acc[i][7];
    *reinterpret_cast<float4*>(C + base) = o0;
    *reinterpret_cast<float4*>(C + base + 64) = o1;
  }
}

// ---------------- iter GEMM C + elementwise --------------------------------------
// B-stage: w = (p0 + p1) - Pvp;  g = V @ w;  e' = clip(e) - P - cg*g (f64).
// BM=BN=128, BK=16, micro 8x8. grid (64,8): x = mt*8 + b.
__global__ __launch_bounds__(256) void k_iterC8(
    const float* __restrict__ Vg, const float* __restrict__ WPg,
    const float* __restrict__ Pvg, const double* __restrict__ Pg,
    double* __restrict__ Eg)
{
  const int b = blockIdx.x & 7, mt = blockIdx.x >> 3;
  const float* A = Vg + (size_t)b * 262144;
  const float* P0 = WPg + (size_t)b * 262144;
  const float* P1 = WPg + ((size_t)8 + b) * 262144;
  const float* Pv = Pvg + (size_t)b * 262144;
  const double* P = Pg + (size_t)b * 1048576;
  double* E = Eg + (size_t)b * 1048576;
  const int m0 = mt * 128, n0 = blockIdx.y * 128;
  const int tid = threadIdx.x;
  __shared__ float As[16][132];
  __shared__ float Bs[16][132];
  const int tx = tid & 15, ty = tid >> 4;
  const int ra = tid >> 1, kqa = (tid & 1) * 8;
  const int rb = tid >> 5, cb = (tid & 31) * 4;
  float acc[8][8] = {};
  for (int k0 = 0; k0 < 256; k0 += 16) {
    // stage A (V, transposed into As[k][m])
    {
      const float4* ap = reinterpret_cast<const float4*>(A + (size_t)(m0 + ra) * 256 + k0 + kqa);
      float4 a0 = ap[0], a1 = ap[1];
      As[kqa + 0][ra] = a0.x; As[kqa + 1][ra] = a0.y; As[kqa + 2][ra] = a0.z; As[kqa + 3][ra] = a0.w;
      As[kqa + 4][ra] = a1.x; As[kqa + 5][ra] = a1.y; As[kqa + 6][ra] = a1.z; As[kqa + 7][ra] = a1.w;
    }
    // stage B: combine partials, subtract Pvp
#pragma unroll
    for (int p = 0; p < 2; ++p) {
      int krow = rb + p * 8;
      size_t off = (size_t)(k0 + krow) * 1024 + n0 + cb;
      float4 q0 = *reinterpret_cast<const float4*>(P0 + off);
      float4 q1 = *reinterpret_cast<const float4*>(P1 + off);
      float4 pv = *reinterpret_cast<const float4*>(Pv + off);
      float4 v;
      v.x = (q0.x + q1.x) - pv.x;
      v.y = (q0.y + q1.y) - pv.y;
      v.z = (q0.z + q1.z) - pv.z;
      v.w = (q0.w + q1.w) - pv.w;
      *reinterpret_cast<float4*>(&Bs[krow][cb]) = v;
    }
    __syncthreads();
#pragma unroll
    for (int kk = 0; kk < 16; ++kk) {
      float4 a0 = *reinterpret_cast<const float4*>(&As[kk][ty * 8]);
      float4 a1 = *reinterpret_cast<const float4*>(&As[kk][ty * 8 + 4]);
      float4 b0 = *reinterpret_cast<const float4*>(&Bs[kk][tx * 4]);
      float4 b1 = *reinterpret_cast<const float4*>(&Bs[kk][tx * 4 + 64]);
      float a_[8] = {a0.x, a0.y, a0.z, a0.w, a1.x, a1.y, a1.z, a1.w};
      float b_[8] = {b0.x, b0.y, b0.z, b0.w, b1.x, b1.y, b1.z, b1.w};
#pragma unroll
      for (int i = 0; i < 8; ++i)
#pragma unroll
        for (int j = 0; j < 8; ++j) acc[i][j] = fmaf(a_[i], b_[j], acc[i][j]);
    }
    __syncthreads();
  }
  // elementwise: two 4-column groups at n0+tx*4 and n0+64+tx*4
  const double cg = 2.0 / 1024.0;
#pragma unroll
  for (int ii = 0; ii < 8; ++ii) {
    size_t row = (size_t)(m0 + ty * 8 + ii) * 1024;
#pragma unroll
    for (int g = 0; g < 2; ++g) {
      size_t base = row + n0 + g * 64 + tx * 4;
      double2 e0 = *reinterpret_cast<const double2*>(E + base);
      double2 e1 = *reinterpret_cast<const double2*>(E + base + 2);
      double2 p0 = *reinterpret_cast<const double2*>(P + base);
      double2 p1 = *reinterpret_cast<const double2*>(P + base + 2);
      double en0 = clip01(e0.x) - p0.x - cg * (double)acc[ii][g * 4 + 0];
      double en1 = clip01(e0.y) - p0.y - cg * (double)acc[ii][g * 4 + 1];
      double en2 = clip01(e1.x) - p1.x - cg * (double)acc[ii][g * 4 + 2];
      double en3 = clip01(e1.y) - p1.y - cg * (double)acc[ii][g * 4 + 3];
      double2 w0; w0.x = en0; w0.y = en1;
      double2 w1; w1.x = en2; w1.y = en3;
      *reinterpret_cast<double2*>(E + base) = w0;
      *reinterpret_cast<double2*>(E + base + 2) = w1;
    }
  }
}

// ---------------- per-(b,n) count -> inverse scale ------------------------------
__global__ __launch_bounds__(256) void k_count(const double* __restrict__ Eg, float* __restrict__ inv)
{
  const int bz = blockIdx.y;
  const int j = blockIdx.x * 256 + threadIdx.x;
  const double* E = Eg + (size_t)bz * 1048576;
  int c = 0;
  for (int i = 0; i < 1024; ++i) c += (E[(size_t)i * 1024 + j] > 0.5) ? 1 : 0;
  inv[bz * 1024 + j] = (float)(1.0 / (((double)c) + 1e-10) / 1024.0);
}

// ---------------- output masked GEMM: out[j,dd] = inv[j] * sum_i mask(e) V[i,dd] --
__global__ __launch_bounds__(256) void k_out(
    const double* __restrict__ Eg, const float* __restrict__ Vg,
    const float* __restrict__ invg, float* __restrict__ Og)
{
  const double* E = Eg + (size_t)blockIdx.z * 1048576;
  const float* Vv = Vg + (size_t)blockIdx.z * 262144;
  const float* inv = invg + blockIdx.z * 1024;
  float* O = Og + (size_t)blockIdx.z * 262144;
  const int j0 = blockIdx.x * 64, d0 = blockIdx.y * 128;
  const int tid = threadIdx.x;
  __shared__ float As[32][68];
  __shared__ float Bs[32][132];
  const int tx = tid & 15, ty = tid >> 4;
  const int ka = tid >> 3, ja = (tid & 7) * 8;
  const int rb = tid >> 5, cbo = (tid & 31) * 4;
  float acc[4][8] = {};
  for (int k0 = 0; k0 < 1024; k0 += 32) {
    {
      const double2* ep = reinterpret_cast<const double2*>(E + (size_t)(k0 + ka) * 1024 + j0 + ja);
      double2 e0 = ep[0], e1 = ep[1], e2 = ep[2], e3 = ep[3];
      As[ka][ja + 0] = (e0.x > 0.5) ? 1.0f : 0.0f;
      As[ka][ja + 1] = (e0.y > 0.5) ? 1.0f : 0.0f;
      As[ka][ja + 2] = (e1.x > 0.5) ? 1.0f : 0.0f;
      As[ka][ja + 3] = (e1.y > 0.5) ? 1.0f : 0.0f;
      As[ka][ja + 4] = (e2.x > 0.5) ? 1.0f : 0.0f;
      As[ka][ja + 5] = (e2.y > 0.5) ? 1.0f : 0.0f;
      As[ka][ja + 6] = (e3.x > 0.5) ? 1.0f : 0.0f;
      As[ka][ja + 7] = (e3.y > 0.5) ? 1.0f : 0.0f;
    }
#pragma unroll
    for (int p = 0; p < 4; ++p) {
      int krow = rb + p * 8;
      float4 bv = *reinterpret_cast<const float4*>(Vv + (size_t)(k0 + krow) * 256 + d0 + cbo);
      *reinterpret_cast<float4*>(&Bs[krow][cbo]) = bv;
    }
    __syncthreads();
#pragma unroll
    for (int kk = 0; kk < 32; ++kk) {
      float4 av = *reinterpret_cast<const float4*>(&As[kk][ty * 4]);
      float4 b0 = *reinterpret_cast<const float4*>(&Bs[kk][tx * 8]);
      float4 b1 = *reinterpret_cast<const float4*>(&Bs[kk][tx * 8 + 4]);
      float a_[4] = {av.x, av.y, av.z, av.w};
      float b_[8] = {b0.x, b0.y, b0.z, b0.w, b1.x, b1.y, b1.z, b1.w};
#pragma unroll
      for (int i = 0; i < 4; ++i)
#pragma unroll
        for (int j = 0; j < 8; ++j) acc[i][j] = fmaf(a_[i], b_[j], acc[i][j]);
    }
    __syncthreads();
  }
#pragma unroll
  for (int i = 0; i < 4; ++i) {
    int row = j0 + ty * 4 + i;
    float sc = inv[row];
    size_t base = (size_t)row * 256 + d0 + tx * 8;
    float4 o0 = {acc[i][0] * sc, acc[i][1] * sc, acc[i][2] * sc, acc[i][3] * sc};
    float4 o1 = {acc[i][4] * sc, acc[i][5] * sc, acc[i][6] * sc, acc[i][7] * sc};
    *reinterpret_cast<float4*>(O + base) = o0;
    *reinterpret_cast<float4*>(O + base + 4) = o1;
  }
}

extern "C" void kernel_launch(void* const* d_in, const int* in_sizes, int n_in,
                              void* d_out, int out_size, void* d_ws, size_t ws_size,
                              hipStream_t stream)
{
  const float* Q = (const float*)d_in[0];   // (8,1024,256)
  const float* V = (const float*)d_in[1];   // (8,1024,256)
  float* out = (float*)d_out;               // (8,1024,256)
  char* ws = (char*)d_ws;

  // workspace layout (bytes) — same 193 MB extent as rounds 1/8
  const size_t OFF_E   = 0;                  // e state, f64 (8,1024,1024)   67MB
  const size_t OFF_P   = 67108864;           // P, f64 (8,1024,1024)         67MB
  const size_t SCR     = 134217728;          // scratch region (33.5 MB)
  const size_t OFF_G   = SCR;
  const size_t OFF_AD  = SCR + 4194304;
  const size_t OFF_X   = SCR + 8388608;
  const size_t OFF_Y   = SCR + 12582912;
  const size_t OFF_X2  = SCR + 16777216;     // final M
  const size_t OFF_PV64= SCR;                // f64 (8,256,1024) overlays G..Y
  const size_t OFF_WP  = SCR;                // fp32 wP [2][8][256][1024] 16.8MB (iters)
  const size_t OFF_W1  = 176160768;          // fp32 W1 (8,256,1024)
  const size_t OFF_PVP = 184549376;          // fp32 Pvp (8,256,1024)
  const size_t OFF_INV = 192937984;          // fp32 (8,1024)

  double* E    = (double*)(ws + OFF_E);
  double* P    = (double*)(ws + OFF_P);
  double* G    = (double*)(ws + OFF_G);
  double* Ad   = (double*)(ws + OFF_AD);
  double* X    = (double*)(ws + OFF_X);
  double* Y    = (double*)(ws + OFF_Y);
  double* X2   = (double*)(ws + OFF_X2);
  double* PV64 = (double*)(ws + OFF_PV64);
  float*  WP   = (float*)(ws + OFF_WP);
  float*  W1   = (float*)(ws + OFF_W1);
  float*  PVP  = (float*)(ws + OFF_PVP);
  float*  INV  = (float*)(ws + OFF_INV);

  (void)in_sizes; (void)n_in; (void)out_size; (void)ws_size;

  // e = 0
  hipMemsetAsync(ws + OFF_E, 0, 67108864, stream);

  // P = (-2/1024) * V @ Q^T + 0.1/1024     (f64, K=256)
  k_gemm_nt<float, double><<<dim3(16, 16, 8), 256, 0, stream>>>(
      V, Q, P, 1024, 1024, 256, 262144, 262144, 1048576, -2.0 / 1024.0, 0.1 / 1024.0);

  // G = (1/1024^2) V^T @ V   (f64, 256x256)
  k_gemm_tn<float><<<dim3(4, 4, 8), 256, 0, stream>>>(
      V, V, G, 256, 256, 1024, 262144, 262144, 65536, 1.0 / 1048576.0);

  // Ad = I + 2G, X0 = I - 2G
  k_adx0<<<dim3(2048), 256, 0, stream>>>(G, Ad, X);

  // Newton-Schulz x3: X <- X(2I - Ad X); final M in X2
  for (int it = 0; it < 3; ++it) {
    const double* Xc = (it % 2 == 0) ? X : X2;
    double* Xn = (it % 2 == 0) ? X2 : X;
    k_smallmm<false><<<dim3(4, 4, 8), 256, 0, stream>>>(
        Ad, Xc, (const double*)nullptr, (void*)Y, 256, 65536, 65536, 1.0, 0.0);
    k_smallmm<false><<<dim3(4, 4, 8), 256, 0, stream>>>(
        Xc, Y, Xc, (void*)Xn, 256, 65536, 65536, -1.0, 2.0);
  }

  // PV64 = (1/1024) V^T @ P   (f64, 256x1024)
  k_gemm_tn<double><<<dim3(4, 16, 8), 256, 0, stream>>>(
      V, P, PV64, 256, 1024, 1024, 262144, 1048576, 262144, 1.0 / 1024.0);

  // PVP = M @ PV64  (fp32 out)
  k_smallmm<true><<<dim3(4, 16, 8), 256, 0, stream>>>(
      X2, PV64, (const double*)nullptr, (void*)PVP, 1024, 262144, 262144, 1.0, 0.0);

  // W1 = (1/1024) M @ V^T  (fp32 out, 256x1024)
  k_gemm_nt<double, float><<<dim3(4, 16, 8), 256, 0, stream>>>(
      X2, V, W1, 256, 1024, 256, 65536, 262144, 262144, 1.0 / 1024.0, 0.0);

  // 50 ADMM iterations (XCD-pinned: bid%8 == batch). s derived from E in iterA.
  for (int t = 0; t < 50; ++t) {
    k_iterA8<<<dim3(32, 8), 256, 0, stream>>>(W1, E, WP);
    k_iterC8<<<dim3(64, 8), 256, 0, stream>>>(V, WP, PVP, P, E);
  }

  // epilogue
  k_count<<<dim3(4, 8), 256, 0, stream>>>(E, INV);
  k_out<<<dim3(16, 2, 8), 256, 0, stream>>>(E, V, INV, out);
}

// Round 12
// 7710.839 us; speedup vs baseline: 1.3521x; 1.0433x over previous
//
#include <hip/hip_runtime.h>

// Problem constants (b=8, n=1024, m=1024, d=256, RHO=1, LAMBDA=0.1, 50 iters)
// ADMM box-QP via Woodbury on A = I + 2 Vs Vs^T  (Vs = V / 1024).
//   state e (f64):  z = clip(e), s = 2z - e   (s derived from E in iterA B-stage)
//   w  = W1 @ s - Pvp   (fp32, K=1024, K-split-4 partials; -Pvp folded into kc==0)
//   e' = clip(e) - P - (2/1024) * (V @ w)   (fp32 GEMM K=256 + f64 elementwise)
// R12 = R11 + iterA K-split 2->4 (512 blocks, 2/CU) with Pvp subtracted in the
// kc==0 partial; iterC combines 4 partials. Tiles/micro/columns as R11.

__device__ __forceinline__ double clip01(double v) { return fmin(fmax(v, 0.0), 1.0); }

// ---------------- NT GEMM, f64 accumulate: C = (TC)(alpha * A@B^T + c0) ----------
template <typename TA, typename TC>
__global__ __launch_bounds__(256) void k_gemm_nt(
    const TA* __restrict__ Ag, const float* __restrict__ Bg, TC* __restrict__ Cg,
    int M, int N, int K, long sA, long sB, long sC, double alpha, double c0)
{
  const TA* A = Ag + (long)blockIdx.z * sA;
  const float* B = Bg + (long)blockIdx.z * sB;
  TC* C = Cg + (long)blockIdx.z * sC;
  const int m0 = blockIdx.x * 64, n0 = blockIdx.y * 64;
  const int tid = threadIdx.x;
  __shared__ double As[32][68];
  __shared__ double Bs[32][68];
  const int tx = tid & 15, ty = tid >> 4;
  const int r = tid >> 2, kq = (tid & 3) * 8;
  double acc[4][4] = {};
  for (int k0 = 0; k0 < K; k0 += 32) {
    if constexpr (sizeof(TA) == 4) {
      const float4* ap = reinterpret_cast<const float4*>(A + (size_t)(m0 + r) * K + k0 + kq);
      float4 a0 = ap[0], a1 = ap[1];
      As[kq+0][r] = a0.x; As[kq+1][r] = a0.y; As[kq+2][r] = a0.z; As[kq+3][r] = a0.w;
      As[kq+4][r] = a1.x; As[kq+5][r] = a1.y; As[kq+6][r] = a1.z; As[kq+7][r] = a1.w;
    } else {
      const double2* ap = reinterpret_cast<const double2*>(A + (size_t)(m0 + r) * K + k0 + kq);
      double2 a0 = ap[0], a1 = ap[1], a2 = ap[2], a3 = ap[3];
      As[kq+0][r] = a0.x; As[kq+1][r] = a0.y; As[kq+2][r] = a1.x; As[kq+3][r] = a1.y;
      As[kq+4][r] = a2.x; As[kq+5][r] = a2.y; As[kq+6][r] = a3.x; As[kq+7][r] = a3.y;
    }
    {
      const float4* bp = reinterpret_cast<const float4*>(B + (size_t)(n0 + r) * K + k0 + kq);
      float4 b0 = bp[0], b1 = bp[1];
      Bs[kq+0][r] = b0.x; Bs[kq+1][r] = b0.y; Bs[kq+2][r] = b0.z; Bs[kq+3][r] = b0.w;
      Bs[kq+4][r] = b1.x; Bs[kq+5][r] = b1.y; Bs[kq+6][r] = b1.z; Bs[kq+7][r] = b1.w;
    }
    __syncthreads();
#pragma unroll
    for (int kk = 0; kk < 32; ++kk) {
      double a_[4], b_[4];
#pragma unroll
      for (int i = 0; i < 4; ++i) a_[i] = As[kk][ty * 4 + i];
#pragma unroll
      for (int j = 0; j < 4; ++j) b_[j] = Bs[kk][tx * 4 + j];
#pragma unroll
      for (int i = 0; i < 4; ++i)
#pragma unroll
        for (int j = 0; j < 4; ++j) acc[i][j] = fma(a_[i], b_[j], acc[i][j]);
    }
    __syncthreads();
  }
#pragma unroll
  for (int i = 0; i < 4; ++i) {
    int row = m0 + ty * 4 + i;
#pragma unroll
    for (int j = 0; j < 4; ++j)
      C[(size_t)row * N + n0 + tx * 4 + j] = (TC)(alpha * acc[i][j] + c0);
  }
}

// ---------------- TN GEMM, f64 accumulate: C[MxN] = scale * A^T @ B -------------
template <typename TB>
__global__ __launch_bounds__(256) void k_gemm_tn(
    const float* __restrict__ Ag, const TB* __restrict__ Bg, double* __restrict__ Cg,
    int M, int N, int K, long sA, long sB, long sC, double scale)
{
  const float* A = Ag + (long)blockIdx.z * sA;
  const TB* B = Bg + (long)blockIdx.z * sB;
  double* C = Cg + (long)blockIdx.z * sC;
  const int m0 = blockIdx.x * 64, n0 = blockIdx.y * 64;
  const int tid = threadIdx.x;
  __shared__ float As[16][68];
  __shared__ double Bs[16][68];
  const int tx = tid & 15, ty = tid >> 4;
  const int kk = tid >> 4, c4 = (tid & 15) * 4;
  double acc[4][4] = {};
  for (int k0 = 0; k0 < K; k0 += 16) {
    float4 av = *reinterpret_cast<const float4*>(A + (size_t)(k0 + kk) * M + m0 + c4);
    *reinterpret_cast<float4*>(&As[kk][c4]) = av;
    if constexpr (sizeof(TB) == 4) {
      float4 bv = *reinterpret_cast<const float4*>(B + (size_t)(k0 + kk) * N + n0 + c4);
      Bs[kk][c4 + 0] = bv.x; Bs[kk][c4 + 1] = bv.y; Bs[kk][c4 + 2] = bv.z; Bs[kk][c4 + 3] = bv.w;
    } else {
      const double2* bp = reinterpret_cast<const double2*>(B + (size_t)(k0 + kk) * N + n0 + c4);
      double2 b0 = bp[0], b1 = bp[1];
      *reinterpret_cast<double2*>(&Bs[kk][c4]) = b0;
      *reinterpret_cast<double2*>(&Bs[kk][c4 + 2]) = b1;
    }
    __syncthreads();
#pragma unroll
    for (int k = 0; k < 16; ++k) {
      double a_[4], b_[4];
#pragma unroll
      for (int i = 0; i < 4; ++i) a_[i] = (double)As[k][ty * 4 + i];
#pragma unroll
      for (int j = 0; j < 4; ++j) b_[j] = Bs[k][tx * 4 + j];
#pragma unroll
      for (int i = 0; i < 4; ++i)
#pragma unroll
        for (int j = 0; j < 4; ++j) acc[i][j] = fma(a_[i], b_[j], acc[i][j]);
    }
    __syncthreads();
  }
#pragma unroll
  for (int i = 0; i < 4; ++i) {
    int row = m0 + ty * 4 + i;
#pragma unroll
    for (int j = 0; j < 4; ++j)
      C[(size_t)row * N + n0 + tx * 4 + j] = scale * acc[i][j];
  }
}

// ---------------- Ad = I + 2G, X0 = I - 2G --------------------------------------
__global__ __launch_bounds__(256) void k_adx0(const double* __restrict__ G,
                                              double* __restrict__ Ad, double* __restrict__ X)
{
  size_t idx = (size_t)blockIdx.x * 256 + threadIdx.x;
  double g = G[idx];
  int ij = (int)(idx & 65535);
  double dg = ((ij >> 8) == (ij & 255)) ? 1.0 : 0.0;
  Ad[idx] = dg + 2.0 * g;
  X[idx] = dg - 2.0 * g;
}

// ---------------- small f64 NN GEMM: C = alpha*A@B + beta*Xin -------------------
template <bool F32OUT>
__global__ __launch_bounds__(256) void k_smallmm(
    const double* __restrict__ Ag, const double* __restrict__ Bg,
    const double* __restrict__ Xg, void* __restrict__ Cg,
    int N, long sB, long sC, double alpha, double beta)
{
  const double* A = Ag + (long)blockIdx.z * 65536;
  const double* B = Bg + (long)blockIdx.z * sB;
  const double* Xp = Xg ? (Xg + (long)blockIdx.z * sB) : (const double*)nullptr;
  const int m0 = blockIdx.x * 64, n0 = blockIdx.y * 64;
  const int tid = threadIdx.x;
  __shared__ double As[16][68];
  __shared__ double Bs[16][68];
  const int tx = tid & 15, ty = tid >> 4;
  const int ra = tid >> 2, kqa = (tid & 3) * 4;
  const int kb = tid >> 4, cb = (tid & 15) * 4;
  double acc[4][4] = {};
  for (int k0 = 0; k0 < 256; k0 += 16) {
    const double2* ap = reinterpret_cast<const double2*>(A + (size_t)(m0 + ra) * 256 + k0 + kqa);
    double2 a0 = ap[0], a1 = ap[1];
    As[kqa + 0][ra] = a0.x; As[kqa + 1][ra] = a0.y; As[kqa + 2][ra] = a1.x; As[kqa + 3][ra] = a1.y;
    const double2* bp = reinterpret_cast<const double2*>(B + (size_t)(k0 + kb) * N + n0 + cb);
    double2 b0 = bp[0], b1 = bp[1];
    *reinterpret_cast<double2*>(&Bs[kb][cb]) = b0;
    *reinterpret_cast<double2*>(&Bs[kb][cb + 2]) = b1;
    __syncthreads();
#pragma unroll
    for (int k = 0; k < 16; ++k) {
      double a_[4], b_[4];
#pragma unroll
      for (int i = 0; i < 4; ++i) a_[i] = As[k][ty * 4 + i];
#pragma unroll
      for (int j = 0; j < 4; ++j) b_[j] = Bs[k][tx * 4 + j];
#pragma unroll
      for (int i = 0; i < 4; ++i)
#pragma unroll
        for (int j = 0; j < 4; ++j) acc[i][j] = fma(a_[i], b_[j], acc[i][j]);
    }
    __syncthreads();
  }
#pragma unroll
  for (int i = 0; i < 4; ++i) {
    int row = m0 + ty * 4 + i;
#pragma unroll
    for (int j = 0; j < 4; ++j) {
      int col = n0 + tx * 4 + j;
      double v = alpha * acc[i][j];
      if (beta != 0.0) v = fma(beta, Xp[(size_t)row * N + col], v);
      if constexpr (F32OUT)
        ((float*)Cg)[(long)blockIdx.z * sC + (size_t)row * N + col] = (float)v;
      else
        ((double*)Cg)[(long)blockIdx.z * sC + (size_t)row * N + col] = v;
    }
  }
}

// ---------------- iter GEMM A: wP[kc] = W1[:, kc-quarter] @ s[kc-quarter, :] ----
// s derived from E on the fly: s = (float)(2*clip(e) - e). kc==0 partial also
// subtracts Pvp. BM=128, BN=128, BK=16, micro 8x8.
// grid (64,8): x = ((mt*4+kc)<<3)|b, y = nt.  512 blocks = 2/CU.
__global__ __launch_bounds__(256) void k_iterA9(
    const float* __restrict__ W1g, const double* __restrict__ Eg,
    const float* __restrict__ Pvg, float* __restrict__ WPg)
{
  const int b = blockIdx.x & 7, kc = (blockIdx.x >> 3) & 3, mt = blockIdx.x >> 5;
  const float* A = W1g + (size_t)b * 262144;      // [256][1024]
  const double* Ee = Eg + (size_t)b * 1048576;    // [1024][1024]
  const float* Pv = Pvg + (size_t)b * 262144;     // [256][1024]
  float* C = WPg + ((size_t)kc * 8 + b) * 262144; // [4][8][256][1024]
  const int m0 = mt * 128, n0 = blockIdx.y * 128;
  const int kbase = kc * 256;
  const int tid = threadIdx.x;
  __shared__ float As[16][132];
  __shared__ float Bs[16][132];
  const int tx = tid & 15, ty = tid >> 4;
  const int ra = tid >> 1, qa = (tid & 1) * 8;    // A stage: row, k-half
  const int kb = tid >> 4, c8 = (tid & 15) * 8;   // B stage
  float acc[8][8] = {};
  for (int k0 = 0; k0 < 256; k0 += 16) {
    // stage A: W1 tile -> As[k][m]
    {
      const float4* ap = reinterpret_cast<const float4*>(A + (size_t)(m0 + ra) * 1024 + kbase + k0 + qa);
      float4 a0 = ap[0], a1 = ap[1];
      As[qa + 0][ra] = a0.x; As[qa + 1][ra] = a0.y; As[qa + 2][ra] = a0.z; As[qa + 3][ra] = a0.w;
      As[qa + 4][ra] = a1.x; As[qa + 5][ra] = a1.y; As[qa + 6][ra] = a1.z; As[qa + 7][ra] = a1.w;
    }
    // stage B: read E rows, convert to s
    {
      const double* erow = Ee + (size_t)(kbase + k0 + kb) * 1024 + n0 + c8;
      double2 e0 = *reinterpret_cast<const double2*>(erow);
      double2 e1 = *reinterpret_cast<const double2*>(erow + 2);
      double2 e2 = *reinterpret_cast<const double2*>(erow + 4);
      double2 e3 = *reinterpret_cast<const double2*>(erow + 6);
      float4 v0, v1;
      v0.x = (float)(2.0 * clip01(e0.x) - e0.x);
      v0.y = (float)(2.0 * clip01(e0.y) - e0.y);
      v0.z = (float)(2.0 * clip01(e1.x) - e1.x);
      v0.w = (float)(2.0 * clip01(e1.y) - e1.y);
      v1.x = (float)(2.0 * clip01(e2.x) - e2.x);
      v1.y = (float)(2.0 * clip01(e2.y) - e2.y);
      v1.z = (float)(2.0 * clip01(e3.x) - e3.x);
      v1.w = (float)(2.0 * clip01(e3.y) - e3.y);
      *reinterpret_cast<float4*>(&Bs[kb][c8]) = v0;
      *reinterpret_cast<float4*>(&Bs[kb][c8 + 4]) = v1;
    }
    __syncthreads();
#pragma unroll
    for (int kk = 0; kk < 16; ++kk) {
      float4 a0 = *reinterpret_cast<const float4*>(&As[kk][ty * 8]);
      float4 a1 = *reinterpret_cast<const float4*>(&As[kk][ty * 8 + 4]);
      float4 b0 = *reinterpret_cast<const float4*>(&Bs[kk][tx * 4]);        // cols tx*4..+3
      float4 b1 = *reinterpret_cast<const float4*>(&Bs[kk][tx * 4 + 64]);   // cols 64+tx*4..+3
      float a_[8] = {a0.x, a0.y, a0.z, a0.w, a1.x, a1.y, a1.z, a1.w};
      float b_[8] = {b0.x, b0.y, b0.z, b0.w, b1.x, b1.y, b1.z, b1.w};
#pragma unroll
      for (int i = 0; i < 8; ++i)
#pragma unroll
        for (int j = 0; j < 8; ++j) acc[i][j] = fmaf(a_[i], b_[j], acc[i][j]);
    }
    __syncthreads();
  }
  if (kc == 0) {
#pragma unroll
    for (int i = 0; i < 8; ++i) {
      size_t base = (size_t)(m0 + ty * 8 + i) * 1024 + n0 + tx * 4;
      float4 pv0 = *reinterpret_cast<const float4*>(Pv + base);
      float4 pv1 = *reinterpret_cast<const float4*>(Pv + base + 64);
      float4 o0; o0.x = acc[i][0] - pv0.x; o0.y = acc[i][1] - pv0.y; o0.z = acc[i][2] - pv0.z; o0.w = acc[i][3] - pv0.w;
      float4 o1; o1.x = acc[i][4] - pv1.x; o1.y = acc[i][5] - pv1.y; o1.z = acc[i][6] - pv1.z; o1.w = acc[i][7] - pv1.w;
      *reinterpret_cast<float4*>(C + base) = o0;
      *reinterpret_cast<float4*>(C + base + 64) = o1;
    }
  } else {
#pragma unroll
    for (int i = 0; i < 8; ++i) {
      size_t base = (size_t)(m0 + ty * 8 + i) * 1024 + n0 + tx * 4;
      float4 o0; o0.x = acc[i][0]; o0.y = acc[i][1]; o0.z = acc[i][2]; o0.w = acc[i][3];
      float4 o1; o1.x = acc[i][4]; o1.y = acc[i][5]; o1.z = acc[i][6]; o1.w = acc[i][7];
      *reinterpret_cast<float4*>(C + base) = o0;
      *reinterpret_cast<float4*>(C + base + 64) = o1;
    }
  }
}

// ---------------- iter GEMM C + elementwise --------------------------------------
// B-stage: w = ((q0+q1)+q2)+q3  (q0 already has -Pvp folded in).
// g = V @ w;  e' = clip(e) - P - cg*g (f64). BM=BN=128, BK=16, micro 8x8.
// grid (64,8): x = mt*8 + b.
__global__ __launch_bounds__(256) void k_iterC9(
    const float* __restrict__ Vg, const float* __restrict__ WPg,
    const double* __restrict__ Pg, double* __restrict__ Eg)
{
  const int b = blockIdx.x & 7, mt = blockIdx.x >> 3;
  const float* A = Vg + (size_t)b * 262144;
  const float* P0 = WPg + (size_t)b * 262144;
  const float* P1 = WPg + ((size_t)8 + b) * 262144;
  const float* P2 = WPg + ((size_t)16 + b) * 262144;
  const float* P3 = WPg + ((size_t)24 + b) * 262144;
  const double* P = Pg + (size_t)b * 1048576;
  double* E = Eg + (size_t)b * 1048576;
  const int m0 = mt * 128, n0 = blockIdx.y * 128;
  const int tid = threadIdx.x;
  __shared__ float As[16][132];
  __shared__ float Bs[16][132];
  const int tx = tid & 15, ty = tid >> 4;
  const int ra = tid >> 1, kqa = (tid & 1) * 8;
  const int rb = tid >> 5, cb = (tid & 31) * 4;
  float acc[8][8] = {};
  for (int k0 = 0; k0 < 256; k0 += 16) {
    // stage A (V, transposed into As[k][m])
    {
      const float4* ap = reinterpret_cast<const float4*>(A + (size_t)(m0 + ra) * 256 + k0 + kqa);
      float4 a0 = ap[0], a1 = ap[1];
      As[kqa + 0][ra] = a0.x; As[kqa + 1][ra] = a0.y; As[kqa + 2][ra] = a0.z; As[kqa + 3][ra] = a0.w;
      As[kqa + 4][ra] = a1.x; As[kqa + 5][ra] = a1.y; As[kqa + 6][ra] = a1.z; As[kqa + 7][ra] = a1.w;
    }
    // stage B: combine 4 partials
#pragma unroll
    for (int p = 0; p < 2; ++p) {
      int krow = rb + p * 8;
      size_t off = (size_t)(k0 + krow) * 1024 + n0 + cb;
      float4 q0 = *reinterpret_cast<const float4*>(P0 + off);
      float4 q1 = *reinterpret_cast<const float4*>(P1 + off);
      float4 q2 = *reinterpret_cast<const float4*>(P2 + off);
      float4 q3 = *reinterpret_cast<const float4*>(P3 + off);
      float4 v;
      v.x = ((q0.x + q1.x) + q2.x) + q3.x;
      v.y = ((q0.y + q1.y) + q2.y) + q3.y;
      v.z = ((q0.z + q1.z) + q2.z) + q3.z;
      v.w = ((q0.w + q1.w) + q2.w) + q3.w;
      *reinterpret_cast<float4*>(&Bs[krow][cb]) = v;
    }
    __syncthreads();
#pragma unroll
    for (int kk = 0; kk < 16; ++kk) {
      float4 a0 = *reinterpret_cast<const float4*>(&As[kk][ty * 8]);
      float4 a1 = *reinterpret_cast<const float4*>(&As[kk][ty * 8 + 4]);
      float4 b0 = *reinterpret_cast<const float4*>(&Bs[kk][tx * 4]);
      float4 b1 = *reinterpret_cast<const float4*>(&Bs[kk][tx * 4 + 64]);
      float a_[8] = {a0.x, a0.y, a0.z, a0.w, a1.x, a1.y, a1.z, a1.w};
      float b_[8] = {b0.x, b0.y, b0.z, b0.w, b1.x, b1.y, b1.z, b1.w};
#pragma unroll
      for (int i = 0; i < 8; ++i)
#pragma unroll
        for (int j = 0; j < 8; ++j) acc[i][j] = fmaf(a_[i], b_[j], acc[i][j]);
    }
    __syncthreads();
  }
  // elementwise: two 4-column groups at n0+tx*4 and n0+64+tx*4
  const double cg = 2.0 / 1024.0;
#pragma unroll
  for (int ii = 0; ii < 8; ++ii) {
    size_t row = (size_t)(m0 + ty * 8 + ii) * 1024;
#pragma unroll
    for (int g = 0; g < 2; ++g) {
      size_t base = row + n0 + g * 64 + tx * 4;
      double2 e0 = *reinterpret_cast<const double2*>(E + base);
      double2 e1 = *reinterpret_cast<const double2*>(E + base + 2);
      double2 p0 = *reinterpret_cast<const double2*>(P + base);
      double2 p1 = *reinterpret_cast<const double2*>(P + base + 2);
      double en0 = clip01(e0.x) - p0.x - cg * (double)acc[ii][g * 4 + 0];
      double en1 = clip01(e0.y) - p0.y - cg * (double)acc[ii][g * 4 + 1];
      double en2 = clip01(e1.x) - p1.x - cg * (double)acc[ii][g * 4 + 2];
      double en3 = clip01(e1.y) - p1.y - cg * (double)acc[ii][g * 4 + 3];
      double2 w0; w0.x = en0; w0.y = en1;
      double2 w1; w1.x = en2; w1.y = en3;
      *reinterpret_cast<double2*>(E + base) = w0;
      *reinterpret_cast<double2*>(E + base + 2) = w1;
    }
  }
}

// ---------------- per-(b,n) count -> inverse scale ------------------------------
__global__ __launch_bounds__(256) void k_count(const double* __restrict__ Eg, float* __restrict__ inv)
{
  const int bz = blockIdx.y;
  const int j = blockIdx.x * 256 + threadIdx.x;
  const double* E = Eg + (size_t)bz * 1048576;
  int c = 0;
  for (int i = 0; i < 1024; ++i) c += (E[(size_t)i * 1024 + j] > 0.5) ? 1 : 0;
  inv[bz * 1024 + j] = (float)(1.0 / (((double)c) + 1e-10) / 1024.0);
}

// ---------------- output masked GEMM: out[j,dd] = inv[j] * sum_i mask(e) V[i,dd] --
__global__ __launch_bounds__(256) void k_out(
    const double* __restrict__ Eg, const float* __restrict__ Vg,
    const float* __restrict__ invg, float* __restrict__ Og)
{
  const double* E = Eg + (size_t)blockIdx.z * 1048576;
  const float* Vv = Vg + (size_t)blockIdx.z * 262144;
  const float* inv = invg + blockIdx.z * 1024;
  float* O = Og + (size_t)blockIdx.z * 262144;
  const int j0 = blockIdx.x * 64, d0 = blockIdx.y * 128;
  const int tid = threadIdx.x;
  __shared__ float As[32][68];
  __shared__ float Bs[32][132];
  const int tx = tid & 15, ty = tid >> 4;
  const int ka = tid >> 3, ja = (tid & 7) * 8;
  const int rb = tid >> 5, cbo = (tid & 31) * 4;
  float acc[4][8] = {};
  for (int k0 = 0; k0 < 1024; k0 += 32) {
    {
      const double2* ep = reinterpret_cast<const double2*>(E + (size_t)(k0 + ka) * 1024 + j0 + ja);
      double2 e0 = ep[0], e1 = ep[1], e2 = ep[2], e3 = ep[3];
      As[ka][ja + 0] = (e0.x > 0.5) ? 1.0f : 0.0f;
      As[ka][ja + 1] = (e0.y > 0.5) ? 1.0f : 0.0f;
      As[ka][ja + 2] = (e1.x > 0.5) ? 1.0f : 0.0f;
      As[ka][ja + 3] = (e1.y > 0.5) ? 1.0f : 0.0f;
      As[ka][ja + 4] = (e2.x > 0.5) ? 1.0f : 0.0f;
      As[ka][ja + 5] = (e2.y > 0.5) ? 1.0f : 0.0f;
      As[ka][ja + 6] = (e3.x > 0.5) ? 1.0f : 0.0f;
      As[ka][ja + 7] = (e3.y > 0.5) ? 1.0f : 0.0f;
    }
#pragma unroll
    for (int p = 0; p < 4; ++p) {
      int krow = rb + p * 8;
      float4 bv = *reinterpret_cast<const float4*>(Vv + (size_t)(k0 + krow) * 256 + d0 + cbo);
      *reinterpret_cast<float4*>(&Bs[krow][cbo]) = bv;
    }
    __syncthreads();
#pragma unroll
    for (int kk = 0; kk < 32; ++kk) {
      float4 av = *reinterpret_cast<const float4*>(&As[kk][ty * 4]);
      float4 b0 = *reinterpret_cast<const float4*>(&Bs[kk][tx * 8]);
      float4 b1 = *reinterpret_cast<const float4*>(&Bs[kk][tx * 8 + 4]);
      float a_[4] = {av.x, av.y, av.z, av.w};
      float b_[8] = {b0.x, b0.y, b0.z, b0.w, b1.x, b1.y, b1.z, b1.w};
#pragma unroll
      for (int i = 0; i < 4; ++i)
#pragma unroll
        for (int j = 0; j < 8; ++j) acc[i][j] = fmaf(a_[i], b_[j], acc[i][j]);
    }
    __syncthreads();
  }
#pragma unroll
  for (int i = 0; i < 4; ++i) {
    int row = j0 + ty * 4 + i;
    float sc = inv[row];
    size_t base = (size_t)row * 256 + d0 + tx * 8;
    float4 o0 = {acc[i][0] * sc, acc[i][1] * sc, acc[i][2] * sc, acc[i][3] * sc};
    float4 o1 = {acc[i][4] * sc, acc[i][5] * sc, acc[i][6] * sc, acc[i][7] * sc};
    *reinterpret_cast<float4*>(O + base) = o0;
    *reinterpret_cast<float4*>(O + base + 4) = o1;
  }
}

extern "C" void kernel_launch(void* const* d_in, const int* in_sizes, int n_in,
                              void* d_out, int out_size, void* d_ws, size_t ws_size,
                              hipStream_t stream)
{
  const float* Q = (const float*)d_in[0];   // (8,1024,256)
  const float* V = (const float*)d_in[1];   // (8,1024,256)
  float* out = (float*)d_out;               // (8,1024,256)
  char* ws = (char*)d_ws;

  // workspace layout (bytes) — same 193 MB extent as rounds 1/8/11
  const size_t OFF_E   = 0;                  // e state, f64 (8,1024,1024)   67MB
  const size_t OFF_P   = 67108864;           // P, f64 (8,1024,1024)         67MB
  const size_t SCR     = 134217728;          // scratch region
  const size_t OFF_G   = SCR;
  const size_t OFF_AD  = SCR + 4194304;
  const size_t OFF_X   = SCR + 8388608;
  const size_t OFF_Y   = SCR + 12582912;
  const size_t OFF_X2  = SCR + 16777216;     // final M
  const size_t OFF_PV64= SCR;                // f64 (8,256,1024) overlays G..Y
  const size_t OFF_WP  = SCR;                // fp32 wP [4][8][256][1024] 33.6MB (iters)
  const size_t OFF_W1  = 176160768;          // fp32 W1 (8,256,1024)
  const size_t OFF_PVP = 184549376;          // fp32 Pvp (8,256,1024)
  const size_t OFF_INV = 192937984;          // fp32 (8,1024)

  double* E    = (double*)(ws + OFF_E);
  double* P    = (double*)(ws + OFF_P);
  double* G    = (double*)(ws + OFF_G);
  double* Ad   = (double*)(ws + OFF_AD);
  double* X    = (double*)(ws + OFF_X);
  double* Y    = (double*)(ws + OFF_Y);
  double* X2   = (double*)(ws + OFF_X2);
  double* PV64 = (double*)(ws + OFF_PV64);
  float*  WP   = (float*)(ws + OFF_WP);
  float*  W1   = (float*)(ws + OFF_W1);
  float*  PVP  = (float*)(ws + OFF_PVP);
  float*  INV  = (float*)(ws + OFF_INV);

  (void)in_sizes; (void)n_in; (void)out_size; (void)ws_size;

  // e = 0
  hipMemsetAsync(ws + OFF_E, 0, 67108864, stream);

  // P = (-2/1024) * V @ Q^T + 0.1/1024     (f64, K=256)
  k_gemm_nt<float, double><<<dim3(16, 16, 8), 256, 0, stream>>>(
      V, Q, P, 1024, 1024, 256, 262144, 262144, 1048576, -2.0 / 1024.0, 0.1 / 1024.0);

  // G = (1/1024^2) V^T @ V   (f64, 256x256)
  k_gemm_tn<float><<<dim3(4, 4, 8), 256, 0, stream>>>(
      V, V, G, 256, 256, 1024, 262144, 262144, 65536, 1.0 / 1048576.0);

  // Ad = I + 2G, X0 = I - 2G
  k_adx0<<<dim3(2048), 256, 0, stream>>>(G, Ad, X);

  // Newton-Schulz x3: X <- X(2I - Ad X); final M in X2
  for (int it = 0; it < 3; ++it) {
    const double* Xc = (it % 2 == 0) ? X : X2;
    double* Xn = (it % 2 == 0) ? X2 : X;
    k_smallmm<false><<<dim3(4, 4, 8), 256, 0, stream>>>(
        Ad, Xc, (const double*)nullptr, (void*)Y, 256, 65536, 65536, 1.0, 0.0);
    k_smallmm<false><<<dim3(4, 4, 8), 256, 0, stream>>>(
        Xc, Y, Xc, (void*)Xn, 256, 65536, 65536, -1.0, 2.0);
  }

  // PV64 = (1/1024) V^T @ P   (f64, 256x1024)
  k_gemm_tn<double><<<dim3(4, 16, 8), 256, 0, stream>>>(
      V, P, PV64, 256, 1024, 1024, 262144, 1048576, 262144, 1.0 / 1024.0);

  // PVP = M @ PV64  (fp32 out)
  k_smallmm<true><<<dim3(4, 16, 8), 256, 0, stream>>>(
      X2, PV64, (const double*)nullptr, (void*)PVP, 1024, 262144, 262144, 1.0, 0.0);

  // W1 = (1/1024) M @ V^T  (fp32 out, 256x1024)
  k_gemm_nt<double, float><<<dim3(4, 16, 8), 256, 0, stream>>>(
      X2, V, W1, 256, 1024, 256, 65536, 262144, 262144, 1.0 / 1024.0, 0.0);

  // 50 ADMM iterations (XCD-pinned: bid%8 == batch). s derived from E in iterA.
  for (int t = 0; t < 50; ++t) {
    k_iterA9<<<dim3(64, 8), 256, 0, stream>>>(W1, E, PVP, WP);
    k_iterC9<<<dim3(64, 8), 256, 0, stream>>>(V, WP, P, E);
  }

  // epilogue
  k_count<<<dim3(4, 8), 256, 0, stream>>>(E, INV);
  k_out<<<dim3(16, 2, 8), 256, 0, stream>>>(E, V, INV, out);
}